// Round 8
// baseline (581.847 us; speedup 1.0000x reference)
//
#include <hip/hip_runtime.h>
#include <hip/hip_bf16.h>
#include <cstdint>
#include <cstddef>

#define NN 1000
#define EE 128000
#define LAYERS 6
#define SCALE 0.125f
#define MAXDEG 320

typedef __attribute__((ext_vector_type(4))) float f32x4;
typedef __attribute__((ext_vector_type(8))) short short8v;

static __device__ __forceinline__ unsigned short f2bf(float x){
    unsigned int u = __float_as_uint(x);
    unsigned int lsb = (u >> 16) & 1u;
    u += 0x7fffu + lsb;
    return (unsigned short)(u >> 16);
}
static __device__ __forceinline__ float bf2f(unsigned short u){
    return __uint_as_float(((unsigned int)u) << 16);
}

// ---------------- sort-by-target (counting sort) ----------------
__global__ void zero_counts(int* cnt){
    cnt[threadIdx.x] = 0;
}

__global__ void hist_kernel(const int* __restrict__ tgt, int* cnt){
    int e = blockIdx.x*256 + threadIdx.x;
    if (e < EE) atomicAdd(&cnt[tgt[e]], 1);
}

__global__ void scan_kernel(const int* __restrict__ cnt, int* offs, int* cursor){
    __shared__ int s[1024];
    int tid = threadIdx.x;
    s[tid] = (tid < NN) ? cnt[tid] : 0;
    __syncthreads();
    for (int st = 1; st < 1024; st <<= 1){
        int v = (tid >= st) ? s[tid-st] : 0;
        __syncthreads();
        s[tid] += v;
        __syncthreads();
    }
    int excl = (tid == 0) ? 0 : s[tid-1];
    if (tid < NN){ offs[tid] = excl; cursor[tid] = excl; }
    if (tid == 0) offs[NN] = s[NN-1];
}

__global__ void scatter_kernel(const int* __restrict__ src, const int* __restrict__ tgt,
                               int* cursor, int* ssrc, int* epos){
    int e = blockIdx.x*256 + threadIdx.x;
    if (e < EE){
        int t = tgt[e];
        int pos = atomicAdd(&cursor[t], 1);
        ssrc[pos] = src[e];
        epos[e] = pos;
    }
}

// ---------------- edge encoder: 4 -> 16 -> 32, bf16 out, sorted order ----------------
__global__ __launch_bounds__(256) void edge_enc(
    const float* __restrict__ edge_attr,
    const float* __restrict__ w1, const float* __restrict__ b1,
    const float* __restrict__ w2, const float* __restrict__ b2,
    const int* __restrict__ epos,
    unsigned short* __restrict__ efs)
{
    __shared__ float w1s[64], b1s[16], w2s[512], b2s[32];
    int tid = threadIdx.x;
    if (tid < 64) w1s[tid] = w1[tid];
    if (tid < 16) b1s[tid] = b1[tid];
    if (tid < 32) b2s[tid] = b2[tid];
    w2s[tid] = w2[tid];
    w2s[tid+256] = w2[tid+256];
    __syncthreads();
    int e = blockIdx.x*256 + tid;
    if (e >= EE) return;
    float4 av = *(const float4*)(edge_attr + (size_t)e*4);
    float hd[16];
    #pragma unroll
    for (int i = 0; i < 16; i++){
        float v = av.x*w1s[i] + av.y*w1s[16+i] + av.z*w1s[32+i] + av.w*w1s[48+i] + b1s[i];
        hd[i] = fmaxf(v, 0.f);
    }
    unsigned short* op = efs + (size_t)epos[e]*32;
    #pragma unroll
    for (int k4 = 0; k4 < 8; k4++){
        ushort4 ub;
        float v0 = b2s[k4*4+0], v1 = b2s[k4*4+1], v2 = b2s[k4*4+2], v3 = b2s[k4*4+3];
        #pragma unroll
        for (int i = 0; i < 16; i++){
            float hv = hd[i];
            v0 += hv*w2s[i*32 + k4*4+0];
            v1 += hv*w2s[i*32 + k4*4+1];
            v2 += hv*w2s[i*32 + k4*4+2];
            v3 += hv*w2s[i*32 + k4*4+3];
        }
        ub.x = f2bf(v0); ub.y = f2bf(v1); ub.z = f2bf(v2); ub.w = f2bf(v3);
        *(ushort4*)(op + k4*4) = ub;
    }
}

// ---------------- merged conversions ----------------
__global__ __launch_bounds__(256) void convert_all(
    const float* __restrict__ Wq, const float* __restrict__ Wk,
    const float* __restrict__ Wv, const float* __restrict__ Ws,
    const float* __restrict__ embed_w, const float* __restrict__ x,
    unsigned short* __restrict__ Wt, unsigned short* __restrict__ ewt,
    unsigned short* __restrict__ xb)
{
    int bid = blockIdx.x;
    int tid = threadIdx.x;
    if (bid < 6144){
        int mm = bid >> 8;
        int tile = bid & 255;
        int tk = tile >> 4, tn = tile & 15;
        int l = mm >> 2, m = mm & 3;
        const float* W = ((m==0)?Wq:(m==1)?Wk:(m==2)?Wv:Ws) + (size_t)l*512*512;
        unsigned short* dst = Wt + (size_t)mm*512*512;
        __shared__ float ts[32][33];
        int r = tid >> 3, c0 = (tid & 7)*4;
        float4 v = *(const float4*)(W + (size_t)(tk*32 + r)*512 + tn*32 + c0);
        ts[r][c0+0] = v.x; ts[r][c0+1] = v.y; ts[r][c0+2] = v.z; ts[r][c0+3] = v.w;
        __syncthreads();
        ushort4 o;
        o.x = f2bf(ts[c0+0][r]); o.y = f2bf(ts[c0+1][r]);
        o.z = f2bf(ts[c0+2][r]); o.w = f2bf(ts[c0+3][r]);
        *(ushort4*)(dst + (size_t)(tn*32 + r)*512 + tk*32 + c0) = o;
    } else if (bid < 6144 + 128){
        int tile = bid - 6144;
        int tn = tile & 15, tk = tile >> 4;
        __shared__ float ts2[32][33];
        int r = tid >> 3, c0 = (tid & 7)*4;
        float4 v = *(const float4*)(embed_w + (size_t)(tk*32 + r)*512 + tn*32 + c0);
        ts2[r][c0+0] = v.x; ts2[r][c0+1] = v.y; ts2[r][c0+2] = v.z; ts2[r][c0+3] = v.w;
        __syncthreads();
        ushort4 o;
        o.x = f2bf(ts2[c0+0][r]); o.y = f2bf(ts2[c0+1][r]);
        o.z = f2bf(ts2[c0+2][r]); o.w = f2bf(ts2[c0+3][r]);
        *(ushort4*)(ewt + (size_t)(tn*32 + r)*256 + tk*32 + c0) = o;
    } else {
        int row = bid - 6144 - 128;
        xb[(size_t)row*256 + tid] = (row < NN) ? f2bf(x[(size_t)row*256 + tid]) : (unsigned short)0;
    }
}

// ---------------- MFMA embed GEMM ----------------
__global__ __launch_bounds__(256) void gemm_embed_mfma(
    const unsigned short* __restrict__ xb,
    const unsigned short* __restrict__ ewt,
    const float* __restrict__ bias, const float* __restrict__ pe,
    float* __restrict__ C, unsigned short* __restrict__ hb)
{
    int bid = blockIdx.x;
    int mt = bid >> 2, nt = bid & 3;
    int row0 = mt*64, col0 = nt*128;

    __shared__ __align__(16) unsigned short As[64*40];
    __shared__ __align__(16) unsigned short Bs[128*40];

    int tid = threadIdx.x;
    int wid = tid >> 6, l = tid & 63;
    int wm = wid >> 1, wn = wid & 1;

    f32x4 acc[2][4] = {};
    int ar = tid >> 2, akq = tid & 3;
    for (int k0 = 0; k0 < 256; k0 += 32){
        *(uint4*)&As[ar*40 + akq*8]      = *(const uint4*)&xb[(size_t)(row0+ar)*256 + k0 + akq*8];
        *(uint4*)&Bs[ar*40 + akq*8]      = *(const uint4*)&ewt[(size_t)(col0+ar)*256 + k0 + akq*8];
        *(uint4*)&Bs[(ar+64)*40 + akq*8] = *(const uint4*)&ewt[(size_t)(col0+ar+64)*256 + k0 + akq*8];
        __syncthreads();
        short8v a0 = *(const short8v*)&As[(wm*32 + (l&15))*40 + (l>>4)*8];
        short8v a1 = *(const short8v*)&As[(wm*32 + 16 + (l&15))*40 + (l>>4)*8];
        #pragma unroll
        for (int nj = 0; nj < 4; nj++){
            short8v b = *(const short8v*)&Bs[(wn*64 + nj*16 + (l&15))*40 + (l>>4)*8];
            acc[0][nj] = __builtin_amdgcn_mfma_f32_16x16x32_bf16(a0, b, acc[0][nj], 0, 0, 0);
            acc[1][nj] = __builtin_amdgcn_mfma_f32_16x16x32_bf16(a1, b, acc[1][nj], 0, 0, 0);
        }
        __syncthreads();
    }
    int rbase = (l >> 4)*4, cl = l & 15;
    #pragma unroll
    for (int mi = 0; mi < 2; mi++)
        #pragma unroll
        for (int nj = 0; nj < 4; nj++)
            #pragma unroll
            for (int r = 0; r < 4; r++){
                int grow = row0 + wm*32 + mi*16 + rbase + r;
                int gcol = col0 + wn*64 + nj*16 + cl;
                if (grow < NN){
                    float v = acc[mi][nj][r] + bias[gcol] + pe[(size_t)grow*512 + gcol];
                    C[(size_t)grow*512 + gcol] = v;
                    hb[(size_t)grow*512 + gcol] = f2bf(v);
                }
            }
}

// ---------------- bf16 MFMA GEMM, 64x64 tiles, reg-prefetch ----------------
__global__ __launch_bounds__(256) void gemm_qkvs_mfma(
    const unsigned short* __restrict__ hb,
    const unsigned short* __restrict__ Wt,
    const float* __restrict__ qb, const float* __restrict__ kb,
    const float* __restrict__ vb, const float* __restrict__ sb,
    float* __restrict__ Q, unsigned short* __restrict__ K16,
    unsigned short* __restrict__ V16, float* __restrict__ S)
{
    int bid = blockIdx.x;
    int mat = bid >> 7;
    int rem = bid & 127;
    int mt = rem >> 3, nt = rem & 7;
    int row0 = mt*64, col0 = nt*64;
    const unsigned short* W = Wt + (size_t)mat*512*512;
    const float* bias = (mat==0)?qb:(mat==1)?kb:(mat==2)?vb:sb;

    __shared__ __align__(16) unsigned short As[64*72];
    __shared__ __align__(16) unsigned short Bs[64*72];

    int tid = threadIdx.x;
    int wid = tid >> 6, l = tid & 63;
    int wm = wid >> 1, wn = wid & 1;

    f32x4 acc[2][2] = {};
    int lr = tid >> 2;
    int lc = (tid & 3)*2;
    const unsigned short* ga = hb + (size_t)(row0+lr)*512 + lc*8;
    const unsigned short* gb = W  + (size_t)(col0+lr)*512 + lc*8;

    uint4 ra0 = *(const uint4*)(ga);
    uint4 ra1 = *(const uint4*)(ga + 8);
    uint4 rb0 = *(const uint4*)(gb);
    uint4 rb1 = *(const uint4*)(gb + 8);

    for (int k0 = 0; k0 < 512; k0 += 64){
        __syncthreads();
        *(uint4*)&As[lr*72 + lc*8]     = ra0;
        *(uint4*)&As[lr*72 + lc*8 + 8] = ra1;
        *(uint4*)&Bs[lr*72 + lc*8]     = rb0;
        *(uint4*)&Bs[lr*72 + lc*8 + 8] = rb1;
        __syncthreads();
        if (k0 + 64 < 512){
            ra0 = *(const uint4*)(ga + k0 + 64);
            ra1 = *(const uint4*)(ga + k0 + 72);
            rb0 = *(const uint4*)(gb + k0 + 64);
            rb1 = *(const uint4*)(gb + k0 + 72);
        }
        #pragma unroll
        for (int ks = 0; ks < 2; ks++){
            short8v a0 = *(const short8v*)&As[(wm*32 + (l&15))*72      + ks*32 + (l>>4)*8];
            short8v a1 = *(const short8v*)&As[(wm*32 + 16 + (l&15))*72 + ks*32 + (l>>4)*8];
            short8v b0 = *(const short8v*)&Bs[(wn*32 + (l&15))*72      + ks*32 + (l>>4)*8];
            short8v b1 = *(const short8v*)&Bs[(wn*32 + 16 + (l&15))*72 + ks*32 + (l>>4)*8];
            acc[0][0] = __builtin_amdgcn_mfma_f32_16x16x32_bf16(a0, b0, acc[0][0], 0, 0, 0);
            acc[0][1] = __builtin_amdgcn_mfma_f32_16x16x32_bf16(a0, b1, acc[0][1], 0, 0, 0);
            acc[1][0] = __builtin_amdgcn_mfma_f32_16x16x32_bf16(a1, b0, acc[1][0], 0, 0, 0);
            acc[1][1] = __builtin_amdgcn_mfma_f32_16x16x32_bf16(a1, b1, acc[1][1], 0, 0, 0);
        }
    }
    int rbase = (l >> 4)*4, cl = l & 15;
    #pragma unroll
    for (int mi = 0; mi < 2; mi++)
        #pragma unroll
        for (int nj = 0; nj < 2; nj++)
            #pragma unroll
            for (int r = 0; r < 4; r++){
                int grow = row0 + wm*32 + mi*16 + rbase + r;
                int gcol = col0 + wn*32 + nj*16 + cl;
                if (grow < NN){
                    float v = acc[mi][nj][r] + bias[gcol];
                    if (mat == 0)      Q[(size_t)grow*512 + gcol] = v;
                    else if (mat == 1) K16[(size_t)grow*512 + gcol] = f2bf(v);
                    else if (mat == 2) V16[(size_t)grow*512 + gcol] = f2bf(v);
                    else               S[(size_t)grow*512 + gcol] = v;
                }
            }
}

// ------------- per-node attention with MFMA scores -------------
// 256 threads (4 waves), one block per node. Scores via block-diagonal GEMM:
// S[e][h] = sum_k [K_row | ef][e][k] * Qbd[k][h], 17 mfma_16x16x32 per 16 edges.
__global__ __launch_bounds__(256) void attn_mfma(
    const float* __restrict__ Qm, const unsigned short* __restrict__ Km,
    const unsigned short* __restrict__ Vm,
    const unsigned short* __restrict__ efs, const float* __restrict__ e_w_l,
    const int* __restrict__ ssrc, const int* __restrict__ offs,
    float* __restrict__ x_pre)
{
    int tid = threadIdx.x;
    int t = blockIdx.x;

    __shared__ float q_s[512];
    __shared__ float qe_s[8*33];
    __shared__ __align__(16) unsigned short qb_s[512];     // bf16 q (k-major)
    __shared__ __align__(16) unsigned short qef_s[64*8];   // step-16 B-frag, lane-major
    __shared__ float sc_s[MAXDEG*8];
    __shared__ int   src_s[MAXDEG];
    __shared__ float pv_s[2][512];
    __shared__ float pe_s[2][256];
    __shared__ float s_s[256];
    __shared__ float redm[32], redd[32];
    __shared__ float m_s[8], d_s[8];

    {
        float v0 = Qm[(size_t)t*512 + tid];
        float v1 = Qm[(size_t)t*512 + 256 + tid];
        q_s[tid] = v0; q_s[256+tid] = v1;
        qb_s[tid] = f2bf(v0); qb_s[256+tid] = f2bf(v1);
    }
    __syncthreads();
    // qe[h][d] = q[h] . e_w[d, h*64..]
    {
        int hh = tid >> 5, dd = tid & 31;
        const float* wrow = e_w_l + (size_t)dd*512 + hh*64;
        const float* qh = q_s + hh*64;
        float a = 0.f;
        #pragma unroll
        for (int c = 0; c < 64; c++) a += qh[c]*wrow[c];
        qe_s[hh*33 + dd] = a;
    }
    __syncthreads();
    // build lane-major B-frag for the ef step: [l][j] = Qbd_ef[(l>>4)*8+j][l&15]
    for (int idx = tid; idx < 512; idx += 256){
        int l = idx >> 3, j = idx & 7;
        int col = l & 15, d = (l >> 4)*8 + j;
        float v = (col < 8) ? qe_s[col*33 + d] : 0.f;
        qef_s[l*8 + j] = f2bf(v);
    }
    int start = offs[t], deg = offs[t+1] - start;
    __syncthreads();

    // ---- phase 1: scores via MFMA. wave wv handles edge-groups [wv*16 + 64m, +16) ----
    {
        int wv = tid >> 6, l = tid & 63;
        int arow = l & 15;            // A row (edge in group) AND B/C col (head)
        int achk = (l >> 4)*8;        // k-chunk within 32-dim step
        const short8v bz = {0,0,0,0,0,0,0,0};
        for (int eg = wv*16; eg < deg; eg += 64){
            int e = eg + arow;
            int ec = (e < deg) ? e : 0;
            int s = ssrc[start + ec];
            if (achk == 0 && e < deg) src_s[e] = s;
            const unsigned short* kr = Km + (size_t)s*512 + achk;
            f32x4 acc = {0.f, 0.f, 0.f, 0.f};
            #pragma unroll
            for (int ks = 0; ks < 16; ks++){
                short8v a = *(const short8v*)(kr + ks*32);
                short8v b = (arow == (ks >> 1)) ? *(const short8v*)(qb_s + ks*32 + achk) : bz;
                acc = __builtin_amdgcn_mfma_f32_16x16x32_bf16(a, b, acc, 0, 0, 0);
            }
            {
                short8v a = *(const short8v*)(efs + (size_t)(start+ec)*32 + achk);
                short8v b = *(const short8v*)(qef_s + l*8);
                acc = __builtin_amdgcn_mfma_f32_16x16x32_bf16(a, b, acc, 0, 0, 0);
            }
            // C: row = (l>>4)*4 + r (local edge), col = l&15 (head)
            #pragma unroll
            for (int r = 0; r < 4; r++){
                int er = eg + (l >> 4)*4 + r;
                if (arow < 8 && er < deg) sc_s[er*8 + arow] = acc[r]*SCALE;
            }
        }
    }
    __syncthreads();

    // ---- max sweep ----
    {
        int he = tid & 7, ib = tid >> 3;
        float lm = -1e30f;
        for (int i = ib; i < deg; i += 32) lm = fmaxf(lm, sc_s[i*8 + he]);
        lm = fmaxf(lm, __shfl_xor(lm, 8));
        lm = fmaxf(lm, __shfl_xor(lm, 16));
        lm = fmaxf(lm, __shfl_xor(lm, 32));
        if ((tid & 63) < 8) redm[(tid>>6)*8 + (tid & 7)] = lm;
    }
    __syncthreads();
    if (tid < 8) m_s[tid] = fmaxf(fmaxf(redm[tid], redm[8+tid]), fmaxf(redm[16+tid], redm[24+tid]));
    __syncthreads();

    // ---- exp sweep + denominator ----
    {
        int he = tid & 7, ib = tid >> 3;
        float mh = m_s[he];
        float den = 0.f;
        for (int i = ib; i < deg; i += 32){
            float al = __expf(sc_s[i*8 + he] - mh);
            sc_s[i*8 + he] = al;
            den += al;
        }
        den += __shfl_xor(den, 8);
        den += __shfl_xor(den, 16);
        den += __shfl_xor(den, 32);
        if ((tid & 63) < 8) redd[(tid>>6)*8 + (tid & 7)] = den;
    }
    __syncthreads();
    if (tid < 8) d_s[tid] = redd[tid] + redd[8+tid] + redd[16+tid] + redd[24+tid];
    __syncthreads();

    // ---- PV + ef accumulation: 2 groups of 128 threads ----
    {
        int g = tid >> 7, q7 = tid & 127;
        int c4 = q7*4;                 // 4 V channels
        int h2 = c4 >> 6;
        int hE = q7 >> 4, dE = (q7 & 15)*2;   // 2 ef dims for head hE
        float4 accV = make_float4(0.f, 0.f, 0.f, 0.f);
        float2 accE = make_float2(0.f, 0.f);
        #pragma unroll 2
        for (int i = g; i < deg; i += 2){
            int s = src_s[i];
            float al = sc_s[i*8 + h2];
            float alE = sc_s[i*8 + hE];
            ushort4 v = *(const ushort4*)(Vm + (size_t)s*512 + c4);
            unsigned int e2 = *(const unsigned int*)(efs + (size_t)(start+i)*32 + dE);
            accV.x += al*bf2f(v.x); accV.y += al*bf2f(v.y);
            accV.z += al*bf2f(v.z); accV.w += al*bf2f(v.w);
            accE.x += alE*bf2f((unsigned short)(e2 & 0xffffu));
            accE.y += alE*bf2f((unsigned short)(e2 >> 16));
        }
        *(float4*)&pv_s[g][c4] = accV;
        *(float2*)&pe_s[g][hE*32 + dE] = accE;
    }
    __syncthreads();
    {
        float dv = d_s[tid >> 5];
        float invd = (dv > 0.f) ? 1.f/dv : 0.f;
        s_s[tid] = (pe_s[0][tid] + pe_s[1][tid]) * invd;
    }
    __syncthreads();

    // ---- output: r + oe for channels tid and tid+256 ----
    {
        int c0 = tid, c1 = tid + 256;
        int h0 = c0 >> 6, h1 = c1 >> 6;
        float dv0 = d_s[h0], dv1 = d_s[h1];
        float i0 = (dv0 > 0.f) ? 1.f/dv0 : 0.f;
        float i1 = (dv1 > 0.f) ? 1.f/dv1 : 0.f;
        float r0 = (pv_s[0][c0] + pv_s[1][c0]) * i0;
        float r1 = (pv_s[0][c1] + pv_s[1][c1]) * i1;
        float oe0 = 0.f, oe1 = 0.f;
        const float* sp0 = s_s + h0*32;
        const float* sp1 = s_s + h1*32;
        #pragma unroll
        for (int d = 0; d < 32; d++){
            oe0 += sp0[d]*e_w_l[(size_t)d*512 + c0];
            oe1 += sp1[d]*e_w_l[(size_t)d*512 + c1];
        }
        x_pre[(size_t)t*512 + c0] = r0 + oe0;
        x_pre[(size_t)t*512 + c1] = r1 + oe1;
    }
}

// ------------- skip + residual + LayerNorm -------------
__global__ __launch_bounds__(256) void ln_skip(
    const float* __restrict__ x_pre, const float* __restrict__ SKm,
    const float* __restrict__ hcur,
    const float* __restrict__ ln_g_l, const float* __restrict__ ln_b_l,
    float* __restrict__ hnext, unsigned short* __restrict__ hbn)
{
    int tid = threadIdx.x, t = blockIdx.x;
    __shared__ float red[4], red2[4];
    float x0 = x_pre[(size_t)t*512 + tid]       + SKm[(size_t)t*512 + tid]       + hcur[(size_t)t*512 + tid];
    float x1 = x_pre[(size_t)t*512 + 256 + tid] + SKm[(size_t)t*512 + 256 + tid] + hcur[(size_t)t*512 + 256 + tid];
    float sA = x0 + x1, sB = x0*x0 + x1*x1;
    #pragma unroll
    for (int m = 1; m <= 32; m <<= 1){
        sA += __shfl_xor(sA, m);
        sB += __shfl_xor(sB, m);
    }
    int wv = tid >> 6, ln = tid & 63;
    if (ln == 0){ red[wv] = sA; red2[wv] = sB; }
    __syncthreads();
    float tot  = red[0] + red[1] + red[2] + red[3];
    float tot2 = red2[0] + red2[1] + red2[2] + red2[3];
    float mu  = tot*(1.f/512.f);
    float var = tot2*(1.f/512.f) - mu*mu;
    float rstd = rsqrtf(var + 1e-5f);
    float y0 = (x0 - mu)*rstd*ln_g_l[tid]     + ln_b_l[tid];
    float y1 = (x1 - mu)*rstd*ln_g_l[256+tid] + ln_b_l[256+tid];
    hnext[(size_t)t*512 + tid]       = y0;
    hnext[(size_t)t*512 + 256 + tid] = y1;
    hbn[(size_t)t*512 + tid]       = f2bf(y0);
    hbn[(size_t)t*512 + 256 + tid] = f2bf(y1);
}

// ---------------- final head: dom + concat + MLP ----------------
__global__ __launch_bounds__(256) void final_head(
    const float* __restrict__ hin,
    const float* __restrict__ dom_w, const float* __restrict__ dom_b,
    const float* __restrict__ w1, const float* __restrict__ b1,
    const float* __restrict__ w2, const float* __restrict__ b2,
    float* __restrict__ out)
{
    int tid = threadIdx.x, t = blockIdx.x;
    __shared__ float h_s[512];
    __shared__ float dom_s[16];
    __shared__ float hid_s[256];
    __shared__ float red[256];
    h_s[tid]     = hin[(size_t)t*512 + tid];
    h_s[tid+256] = hin[(size_t)t*512 + 256 + tid];
    __syncthreads();
    if (tid < 16){
        float a = dom_b[tid];
        for (int i = 0; i < 512; i++) a += h_s[i]*dom_w[i*16 + tid];
        dom_s[tid] = a;
    }
    __syncthreads();
    float acc = b1[tid];
    for (int i = 0; i < 512; i++) acc += h_s[i]*w1[(size_t)i*256 + tid];
    #pragma unroll
    for (int i = 0; i < 16; i++) acc += dom_s[i]*w1[(size_t)(512+i)*256 + tid];
    hid_s[tid] = fmaxf(acc, 0.f);
    __syncthreads();
    int o = tid & 15, g = tid >> 4;
    float p = 0.f;
    #pragma unroll
    for (int j = 0; j < 16; j++) p += hid_s[g*16 + j]*w2[(g*16 + j)*16 + o];
    red[tid] = p;
    __syncthreads();
    if (tid < 16){
        float s2 = b2[tid];
        for (int gg = 0; gg < 16; gg++) s2 += red[gg*16 + tid];
        out[(size_t)t*16 + tid] = s2;
    }
}

// ---------------- launch ----------------
extern "C" void kernel_launch(void* const* d_in, const int* in_sizes, int n_in,
                              void* d_out, int out_size, void* d_ws, size_t ws_size,
                              hipStream_t stream)
{
    const float* x       = (const float*)d_in[0];
    const int*   eidx    = (const int*)  d_in[1];
    const float* eattr   = (const float*)d_in[2];
    const float* embed_w = (const float*)d_in[3];
    const float* embed_b = (const float*)d_in[4];
    const float* pe      = (const float*)d_in[5];
    const float* ee_w1   = (const float*)d_in[6];
    const float* ee_b1   = (const float*)d_in[7];
    const float* ee_w2   = (const float*)d_in[8];
    const float* ee_b2   = (const float*)d_in[9];
    const float* q_w     = (const float*)d_in[10];
    const float* q_b     = (const float*)d_in[11];
    const float* k_w     = (const float*)d_in[12];
    const float* k_b     = (const float*)d_in[13];
    const float* v_w     = (const float*)d_in[14];
    const float* v_b     = (const float*)d_in[15];
    const float* e_w     = (const float*)d_in[16];
    const float* skip_w  = (const float*)d_in[17];
    const float* skip_b  = (const float*)d_in[18];
    const float* ln_g    = (const float*)d_in[19];
    const float* ln_b    = (const float*)d_in[20];
    const float* dom_w   = (const float*)d_in[21];
    const float* dom_b   = (const float*)d_in[22];
    const float* cls_w1  = (const float*)d_in[23];
    const float* cls_b1  = (const float*)d_in[24];
    const float* cls_w2  = (const float*)d_in[25];
    const float* cls_b2  = (const float*)d_in[26];
    float* out = (float*)d_out;

    float* ws = (float*)d_ws;
    size_t o = 0;
    float* h0    = ws + o; o += (size_t)512*NN;
    float* h1    = ws + o; o += (size_t)512*NN;
    float* Qb    = ws + o; o += (size_t)512*NN;
    float* Sb    = ws + o; o += (size_t)512*NN;
    float* xpre  = ws + o; o += (size_t)512*NN;
    unsigned short* Kb16 = (unsigned short*)(ws + o); o += (size_t)1024*512/2;
    unsigned short* Vb16 = (unsigned short*)(ws + o); o += (size_t)1024*512/2;
    unsigned short* efs  = (unsigned short*)(ws + o); o += (size_t)EE*32/2;
    unsigned short* hb   = (unsigned short*)(ws + o); o += (size_t)1024*512/2;
    unsigned short* xb   = (unsigned short*)(ws + o); o += (size_t)1024*256/2;
    unsigned short* ewt  = (unsigned short*)(ws + o); o += (size_t)512*256/2;
    unsigned short* Wtb  = (unsigned short*)(ws + o); o += (size_t)24*512*512/2;
    int* cnt    = (int*)(ws + o); o += 1024;
    int* offs   = (int*)(ws + o); o += 1024;
    int* cursor = (int*)(ws + o); o += 1024;
    int* ssrc   = (int*)(ws + o); o += EE;
    int* epos   = (int*)(ws + o); o += EE;

    const int* srcp = eidx;
    const int* tgtp = eidx + EE;

    zero_counts<<<1, 1024, 0, stream>>>(cnt);
    hist_kernel<<<EE/256, 256, 0, stream>>>(tgtp, cnt);
    scan_kernel<<<1, 1024, 0, stream>>>(cnt, offs, cursor);
    scatter_kernel<<<EE/256, 256, 0, stream>>>(srcp, tgtp, cursor, ssrc, epos);
    edge_enc<<<EE/256, 256, 0, stream>>>(eattr, ee_w1, ee_b1, ee_w2, ee_b2, epos, efs);
    convert_all<<<6144 + 128 + 1024, 256, 0, stream>>>(q_w, k_w, v_w, skip_w, embed_w, x, Wtb, ewt, xb);
    gemm_embed_mfma<<<64, 256, 0, stream>>>(xb, ewt, embed_b, pe, h0, hb);

    float* hc = h0;
    float* hn = h1;
    for (int l = 0; l < LAYERS; l++){
        gemm_qkvs_mfma<<<512, 256, 0, stream>>>(
            hb, Wtb + (size_t)l*4*512*512,
            q_b + (size_t)l*512, k_b + (size_t)l*512,
            v_b + (size_t)l*512, skip_b + (size_t)l*512,
            Qb, Kb16, Vb16, Sb);
        attn_mfma<<<NN, 256, 0, stream>>>(
            Qb, Kb16, Vb16, efs, e_w + (size_t)l*32*512,
            ssrc, offs, xpre);
        ln_skip<<<NN, 256, 0, stream>>>(
            xpre, Sb, hc,
            ln_g + (size_t)l*512, ln_b + (size_t)l*512,
            hn, hb);
        float* tmp = hc; hc = hn; hn = tmp;
    }
    final_head<<<NN, 256, 0, stream>>>(hc, dom_w, dom_b, cls_w1, cls_b1, cls_w2, cls_b2, out);
}